// Round 1
// baseline (16.722 us; speedup 1.0000x reference)
//
#include <hip/hip_runtime.h>
#include <math.h>

#define BB 16
#define PP 20
#define NPARTS 17
#define DD 32
#define HH 128
#define WW 128
#define HWN (HH*WW)
#define CC (NPARTS*DD)   // 544 channels

// Block-wide sum for 256 threads (4 wave64s).
__device__ __forceinline__ float block_sum_256(float v, float* wsum) {
    #pragma unroll
    for (int off = 32; off > 0; off >>= 1) v += __shfl_down(v, off);
    int lane = threadIdx.x & 63;
    int wid  = threadIdx.x >> 6;
    if (lane == 0) wsum[wid] = v;
    __syncthreads();
    float t = 0.f;
    if (threadIdx.x == 0) t = wsum[0] + wsum[1] + wsum[2] + wsum[3];
    return t;  // valid on thread 0 only
}

// One block per (b,p): gather 17x32 embedding vecs, compute mean + pull.
__global__ __launch_bounds__(256) void k1_gather_pull(
        const float* __restrict__ ebd, const float* __restrict__ kpts,
        float* __restrict__ means, float* __restrict__ pull_pp) {
    const int bp  = blockIdx.x;        // b*PP + p
    const int b   = bp / PP;
    const int tid = threadIdx.x;

    __shared__ float vec[CC];
    __shared__ int   lin[NPARTS];
    __shared__ float mean_s[DD];
    __shared__ float wsum[4];

    if (tid < NPARTS) {
        float ky = kpts[(bp * NPARTS + tid) * 2 + 0];
        float kx = kpts[(bp * NPARTS + tid) * 2 + 1];
        int y = (int)floorf(ky * (float)HH);
        int x = (int)floorf(kx * (float)WW);
        y = min(max(y, 0), HH - 1);
        x = min(max(x, 0), WW - 1);
        lin[tid] = y * WW + x;
    }
    __syncthreads();

    const float* base = ebd + (size_t)b * CC * HWN;
    for (int i = tid; i < CC; i += 256) {
        int k = i >> 5;                       // part index (i = k*32 + d)
        vec[i] = base[(size_t)i * HWN + lin[k]];
    }
    __syncthreads();

    if (tid < DD) {
        float s = 0.f;
        #pragma unroll
        for (int k = 0; k < NPARTS; ++k) s += vec[k * DD + tid];
        float m = s * (1.0f / (float)NPARTS);
        mean_s[tid] = m;
        means[bp * DD + tid] = m;
    }
    __syncthreads();

    float ps = 0.f;
    for (int i = tid; i < CC; i += 256)
        ps += fabsf(vec[i] - mean_s[i & (DD - 1)]);

    float tot = block_sum_256(ps, wsum);
    if (tid == 0) pull_pp[bp] = tot * (1.0f / (float)CC);
}

// One block per batch: mean pairwise |mean_p - mean_q| over P*P*D terms.
__global__ __launch_bounds__(256) void k2_push(
        const float* __restrict__ means, float* __restrict__ push_b) {
    const int b   = blockIdx.x;
    const int tid = threadIdx.x;

    __shared__ float m[PP * DD];
    __shared__ float wsum[4];

    for (int i = tid; i < PP * DD; i += 256)
        m[i] = means[b * PP * DD + i];
    __syncthreads();

    float ps = 0.f;
    for (int i = tid; i < PP * PP * DD; i += 256) {
        int d  = i & (DD - 1);
        int pq = i >> 5;
        int p  = pq / PP;
        int q  = pq - p * PP;
        ps += fabsf(m[p * DD + d] - m[q * DD + d]);
    }

    float tot = block_sum_256(ps, wsum);
    if (tid == 0) push_b[b] = tot * (1.0f / (float)(PP * PP * DD));
}

// Final combine: out = (pull.mean_b + push.mean_b) / 2
//              = (sum(pull_pp) + sum(push_b)) / (2*B)
__global__ __launch_bounds__(256) void k3_final(
        const float* __restrict__ pull_pp, const float* __restrict__ push_b,
        float* __restrict__ out) {
    const int tid = threadIdx.x;
    __shared__ float wsum[4];

    float s = 0.f;
    for (int i = tid; i < BB * PP; i += 256) s += pull_pp[i];
    if (tid < BB) s += push_b[tid];

    float tot = block_sum_256(s, wsum);
    if (tid == 0) out[0] = tot * (1.0f / (2.0f * (float)BB));
}

extern "C" void kernel_launch(void* const* d_in, const int* in_sizes, int n_in,
                              void* d_out, int out_size, void* d_ws, size_t ws_size,
                              hipStream_t stream) {
    const float* ebd  = (const float*)d_in[0];   // [16, 544, 128, 128] f32
    const float* kpts = (const float*)d_in[1];   // [16, 20, 17, 2] f32
    float* out = (float*)d_out;                  // scalar f32

    float* ws       = (float*)d_ws;
    float* means    = ws;                        // B*P*D = 10240 floats
    float* pull_pp  = means + BB * PP * DD;      // B*P   = 320 floats
    float* push_b   = pull_pp + BB * PP;         // B     = 16 floats

    k1_gather_pull<<<BB * PP, 256, 0, stream>>>(ebd, kpts, means, pull_pp);
    k2_push<<<BB, 256, 0, stream>>>(means, push_b);
    k3_final<<<1, 256, 0, stream>>>(pull_pp, push_b, out);
}

// Round 2
// 16.059 us; speedup vs baseline: 1.0413x; 1.0413x over previous
//
#include <hip/hip_runtime.h>
#include <math.h>

#define BB 16
#define PP 20
#define NPARTS 17
#define DD 32
#define HH 128
#define WW 128
#define HWN (HH*WW)
#define CC (NPARTS*DD)   // 544 channels

// Block-wide sum for 256 threads (4 wave64s). Valid on thread 0 only.
__device__ __forceinline__ float block_sum_256(float v, float* wsum) {
    #pragma unroll
    for (int off = 32; off > 0; off >>= 1) v += __shfl_down(v, off);
    int lane = threadIdx.x & 63;
    int wid  = threadIdx.x >> 6;
    if (lane == 0) wsum[wid] = v;
    __syncthreads();
    float t = 0.f;
    if (threadIdx.x == 0) t = wsum[0] + wsum[1] + wsum[2] + wsum[3];
    return t;
}

// K1 — one block per (b,p): gather 17x32 embedding vecs, compute mean + pull
// partial. Block 0 also zeroes the arrival counter used by K2 (ordered by the
// dispatch boundary; re-zeroed every call so graph replays are deterministic).
__global__ __launch_bounds__(256) void k1_gather_pull(
        const float* __restrict__ ebd, const float* __restrict__ kpts,
        float* __restrict__ means, float* __restrict__ pull_pp,
        unsigned int* __restrict__ counter) {
    const int bp  = blockIdx.x;        // b*PP + p
    const int b   = bp / PP;
    const int tid = threadIdx.x;

    if (bp == 0 && tid == 0) *counter = 0u;

    __shared__ float vec[CC];
    __shared__ int   lin[NPARTS];
    __shared__ float mean_s[DD];
    __shared__ float wsum[4];

    if (tid < NPARTS) {
        float ky = kpts[(bp * NPARTS + tid) * 2 + 0];
        float kx = kpts[(bp * NPARTS + tid) * 2 + 1];
        int y = (int)floorf(ky * (float)HH);
        int x = (int)floorf(kx * (float)WW);
        y = min(max(y, 0), HH - 1);
        x = min(max(x, 0), WW - 1);
        lin[tid] = y * WW + x;
    }
    __syncthreads();

    const float* base = ebd + (size_t)b * CC * HWN;
    for (int i = tid; i < CC; i += 256) {
        int k = i >> 5;                       // part index (i = k*32 + d)
        vec[i] = base[(size_t)i * HWN + lin[k]];
    }
    __syncthreads();

    if (tid < DD) {
        float s = 0.f;
        #pragma unroll
        for (int k = 0; k < NPARTS; ++k) s += vec[k * DD + tid];
        float m = s * (1.0f / (float)NPARTS);
        mean_s[tid] = m;
        means[bp * DD + tid] = m;
    }
    __syncthreads();

    float ps = 0.f;
    for (int i = tid; i < CC; i += 256)
        ps += fabsf(vec[i] - mean_s[i & (DD - 1)]);

    float tot = block_sum_256(ps, wsum);
    if (tid == 0) pull_pp[bp] = tot * (1.0f / (float)CC);
}

// K2 — one block per batch b: push term (register-blocked float4, full PxP
// including diagonal, exactly mirroring the reference sum) + this batch's
// pull partials -> partial_b[b]. Last block to arrive sums the 16 partials
// in fixed order and writes the scalar output.
__global__ __launch_bounds__(256) void k2_push_final(
        const float* __restrict__ means, const float* __restrict__ pull_pp,
        float* __restrict__ partial_b, unsigned int* __restrict__ counter,
        float* __restrict__ out) {
    const int b   = blockIdx.x;
    const int tid = threadIdx.x;

    __shared__ float m[PP * DD];
    __shared__ float wsum[4];

    for (int i = tid; i < PP * DD; i += 256)
        m[i] = means[b * PP * DD + i];
    __syncthreads();

    // push: thread t<160 owns (p = t/8, d4 = t%8), holds m[p][d4*4..] in regs,
    // loops q (LDS broadcast across lanes sharing d4).
    float acc = 0.f;
    if (tid < PP * (DD / 4)) {
        int p  = tid >> 3;
        int d4 = tid & 7;
        float4 mp = *reinterpret_cast<const float4*>(&m[p * DD + d4 * 4]);
        #pragma unroll
        for (int q = 0; q < PP; ++q) {
            float4 mq = *reinterpret_cast<const float4*>(&m[q * DD + d4 * 4]);
            acc += fabsf(mp.x - mq.x) + fabsf(mp.y - mq.y)
                 + fabsf(mp.z - mq.z) + fabsf(mp.w - mq.w);
        }
    }
    float v = acc * (1.0f / (float)(PP * PP * DD));
    if (tid < PP) v += pull_pp[b * PP + tid];     // pull_b = sum of 20 partials

    float tot = block_sum_256(v, wsum);

    if (tid == 0) {
        __hip_atomic_store(&partial_b[b], tot, __ATOMIC_RELEASE,
                           __HIP_MEMORY_SCOPE_AGENT);
        unsigned int old = __hip_atomic_fetch_add(counter, 1u, __ATOMIC_ACQ_REL,
                                                  __HIP_MEMORY_SCOPE_AGENT);
        if (old == BB - 1) {
            float s = 0.f;
            #pragma unroll
            for (int i = 0; i < BB; ++i)
                s += __hip_atomic_load(&partial_b[i], __ATOMIC_ACQUIRE,
                                       __HIP_MEMORY_SCOPE_AGENT);
            out[0] = s * (1.0f / (2.0f * (float)BB));
        }
    }
}

extern "C" void kernel_launch(void* const* d_in, const int* in_sizes, int n_in,
                              void* d_out, int out_size, void* d_ws, size_t ws_size,
                              hipStream_t stream) {
    const float* ebd  = (const float*)d_in[0];   // [16, 544, 128, 128] f32
    const float* kpts = (const float*)d_in[1];   // [16, 20, 17, 2] f32
    float* out = (float*)d_out;                  // scalar f32

    float* ws            = (float*)d_ws;
    float* means         = ws;                        // 10240 floats
    float* pull_pp       = means + BB * PP * DD;      // 320 floats
    float* partial_b     = pull_pp + BB * PP;         // 16 floats
    unsigned int* counter = (unsigned int*)(partial_b + BB);

    k1_gather_pull<<<BB * PP, 256, 0, stream>>>(ebd, kpts, means, pull_pp, counter);
    k2_push_final<<<BB, 256, 0, stream>>>(means, pull_pp, partial_b, counter, out);
}